// Round 2
// baseline (137.726 us; speedup 1.0000x reference)
//
#include <hip/hip_runtime.h>
#include <math.h>

#define DIM 64
#define BATCH 4096

// Kernel 1: squeezed vacuum s = expm(0.25*(a^2 - adag^2)) @ vacuum  (real, 64-dim)
// One wave; lane i holds v[i]. Pentadiagonal matvec via shuffles.
// (M v)[i] = 0.25*( sqrt((i+1)(i+2)) v[i+2] - sqrt(i(i-1)) v[i-2] )
__global__ void squeeze_kernel(const float* __restrict__ vac, float* __restrict__ ws) {
    const int i = threadIdx.x;            // 0..63
    float cu = (i < DIM - 2) ? sqrtf((float)((i + 1) * (i + 2))) : 0.f;
    float cd = (i >= 2)      ? sqrtf((float)(i * (i - 1)))       : 0.f;
    const int   NS = 64;                  // ||M|| <= 31.2 -> step norm <= 0.49
    const float sc = 0.25f / (float)NS;
    float v = vac[i];                     // e0 per reference
    for (int s = 0; s < NS; ++s) {
        float t = v, w = v;
        #pragma unroll
        for (int k = 1; k <= 12; ++k) {
            float tp = __shfl(t, i + 2, 64);
            float tm = __shfl(t, i - 2, 64);   // gated by cd=0 at i<2
            t = (cu * tp - cd * tm) * (sc / (float)k);
            w += t;
        }
        v = w;
    }
    ws[i] = v;
}

// Kernel 2: one wave per batch element.
// psi = normalize( expm(alpha*(adag - a)) @ s );  rho[i][j] = psi_i*psi_j (imag = 0)
// (M v)[i] = alpha*( sqrt(i) v[i-1] - sqrt(i+1) v[i+1] )
// interleaved==1: out is complex64 pairs (re,0); interleaved==0: out is real floats.
__global__ __launch_bounds__(256) void displace_kernel(const float* __restrict__ x,
                                                       const float* __restrict__ sv,
                                                       float* __restrict__ out,
                                                       int interleaved) {
    const int lane = threadIdx.x & 63;
    const int b = blockIdx.x * (blockDim.x >> 6) + (threadIdx.x >> 6);  // batch idx

    const float alpha = 0.5f * x[b];
    float v = sv[lane];
    const float cu = (lane < DIM - 1) ? sqrtf((float)(lane + 1)) : 0.f;
    const float cd = sqrtf((float)lane);   // 0 at lane 0

    // adaptive scaling: ||alpha*(adag-a)|| <= 16|alpha|; n steps -> step norm <= 0.5
    float aa = fabsf(alpha);
    int n = (int)ceilf(aa * 32.f);
    if (n < 1) n = 1;
    const float sc = alpha / (float)n;

    for (int s = 0; s < n; ++s) {
        float t = v, w = v;
        #pragma unroll
        for (int k = 1; k <= 12; ++k) {
            float tm = __shfl(t, lane - 1, 64);  // gated by cd=0 at lane 0
            float tp = __shfl(t, lane + 1, 64);  // gated by cu=0 at lane 63
            t = (cd * tm - cu * tp) * (sc / (float)k);
            w += t;
        }
        v = w;
    }

    // normalize (exp of antisymmetric is orthogonal, so n2 ~= 1; match reference anyway)
    float n2 = v * v;
    #pragma unroll
    for (int off = 32; off; off >>= 1) n2 += __shfl_xor(n2, off, 64);
    v *= rsqrtf(n2);

    if (interleaved) {
        // complex64 layout: interleaved (re, im); im = 0 exactly
        float2* o = (float2*)out + (size_t)b * (DIM * DIM);
        #pragma unroll 8
        for (int r = 0; r < DIM; ++r) {
            float vr = __shfl(v, r, 64);
            o[r * DIM + lane] = make_float2(vr * v, 0.f);
        }
    } else {
        // real-only float32 buffer (imag of rho is exactly 0 in the reference)
        float* o = out + (size_t)b * (DIM * DIM);
        #pragma unroll 8
        for (int r = 0; r < DIM; ++r) {
            float vr = __shfl(v, r, 64);
            o[r * DIM + lane] = vr * v;
        }
    }
}

extern "C" void kernel_launch(void* const* d_in, const int* in_sizes, int n_in,
                              void* d_out, int out_size, void* d_ws, size_t ws_size,
                              hipStream_t stream) {
    const float* x   = (const float*)d_in[0];   // (4096,) float32
    const float* vac = (const float*)d_in[1];   // (64,1) float32
    float* out = (float*)d_out;
    float* sv  = (float*)d_ws;                  // 64 floats: squeezed vacuum

    // complex64 output may be exposed as either N real elements (imag dropped,
    // compared with imag=0) or 2N interleaved floats. Never write past out_size.
    const int N = BATCH * DIM * DIM;
    const int interleaved = (out_size >= 2 * N) ? 1 : 0;

    squeeze_kernel<<<1, 64, 0, stream>>>(vac, sv);
    displace_kernel<<<BATCH / 4, 256, 0, stream>>>(x, sv, out, interleaved);
}

// Round 3
// 78.420 us; speedup vs baseline: 1.7563x; 1.7563x over previous
//
#include <hip/hip_runtime.h>
#include <math.h>

#define DIM 64
#define BATCH 4096

// One wave per batch element. Closed-form amplitudes of psi = D(alpha) S(r) |0>:
//   psi_{n+1} = (alpha*(1+tanh r)*psi_n - tanh r*sqrt(n)*psi_{n-1}) / sqrt(n+1)
// (from (cosh r * a + sinh r * a^dag) psi = alpha e^r psi; psi_0 = 1, normalize after).
// All 64 lanes run the 63-step recurrence redundantly (wave-uniform VALU, no
// shuffles in the chain); lane n latches psi_n. Then butterfly-normalize and
// write rho[b][i][j] = psi_i psi_j (imag exactly 0).
__global__ __launch_bounds__(256) void qencoder_kernel(const float* __restrict__ x,
                                                       float* __restrict__ out,
                                                       int interleaved) {
    const int lane = threadIdx.x & 63;
    const int b = blockIdx.x * (blockDim.x >> 6) + (threadIdx.x >> 6);  // batch idx

    const float TANH_R = 0.46211715726f;   // tanh(0.5)
    const float alpha = 0.5f * x[b];
    const float c1 = alpha * (1.0f + TANH_R);   // alpha * e^r / cosh r

    // 63-step recurrence, fully unrolled (sqrt(n), rsqrt(n+1) fold to literals)
    float pm1 = 1.0f;           // psi_{n-1} -> starts as psi_0
    float p   = c1;             // psi_1 = c1 * psi_0
    float v = (lane == 0) ? 1.0f : 0.0f;
    if (lane == 1) v = p;
    #pragma unroll
    for (int n = 1; n < DIM - 1; ++n) {
        float pn = (c1 * p - TANH_R * sqrtf((float)n) * pm1) * rsqrtf((float)(n + 1));
        pm1 = p;
        p = pn;
        if (lane == n + 1) v = pn;
    }

    // normalize
    float n2 = v * v;
    #pragma unroll
    for (int off = 32; off; off >>= 1) n2 += __shfl_xor(n2, off, 64);
    v *= rsqrtf(n2);

    // column values for this lane's two columns (2c, 2c+1), c = lane&31
    const int cp = lane & 31;
    const int rs = lane >> 5;                   // row-select within a pair
    float pc0 = __shfl(v, 2 * cp, 64);
    float pc1 = __shfl(v, 2 * cp + 1, 64);

    if (interleaved) {
        // complex64: (re, im) pairs, im = 0. float4 = 2 complex elements.
        float4* o4 = (float4*)out + (size_t)b * (DIM * DIM / 2);
        #pragma unroll
        for (int i = 0; i < DIM / 2; ++i) {
            int row = 2 * i + rs;
            float vr = __shfl(v, row, 64);
            o4[row * (DIM / 2) + cp] = make_float4(vr * pc0, 0.f, vr * pc1, 0.f);
        }
    } else {
        // real-only float buffer (imag of rho is exactly 0)
        float2* o2 = (float2*)out + (size_t)b * (DIM * DIM / 2);
        #pragma unroll
        for (int i = 0; i < DIM / 2; ++i) {
            int row = 2 * i + rs;
            float vr = __shfl(v, row, 64);
            o2[row * (DIM / 2) + cp] = make_float2(vr * pc0, vr * pc1);
        }
    }
}

extern "C" void kernel_launch(void* const* d_in, const int* in_sizes, int n_in,
                              void* d_out, int out_size, void* d_ws, size_t ws_size,
                              hipStream_t stream) {
    const float* x = (const float*)d_in[0];   // (4096,) float32
    float* out = (float*)d_out;

    const int N = BATCH * DIM * DIM;
    const int interleaved = (out_size >= 2 * N) ? 1 : 0;

    qencoder_kernel<<<BATCH / 4, 256, 0, stream>>>(x, out, interleaved);
}

// Round 5
// 78.180 us; speedup vs baseline: 1.7617x; 1.0031x over previous
//
#include <hip/hip_runtime.h>
#include <math.h>

#define DIM 64
#define BATCH 4096

// clang-native vector types (HIP's float4 is a class; the nontemporal builtin
// requires a true vector-of-scalars type)
typedef float vf4 __attribute__((ext_vector_type(4)));
typedef float vf2 __attribute__((ext_vector_type(2)));

// One wave per batch element. Closed-form amplitudes of psi = D(alpha) S(r) |0>:
//   psi_{n+1} = (alpha*(1+tanh r)*psi_n - tanh r*sqrt(n)*psi_{n-1}) / sqrt(n+1)
// (from (cosh r * a + sinh r * a^dag) psi = alpha e^r psi; psi_0 = 1, normalize after).
// All 64 lanes run the 63-step recurrence redundantly (wave-uniform VALU, no
// shuffles in the chain); lane n latches psi_n. Then butterfly-normalize and
// write rho[b][i][j] = psi_i psi_j (imag exactly 0) via nontemporal stores
// (pure streaming write, no reuse -> bypass L2 allocate).
__global__ __launch_bounds__(256) void qencoder_kernel(const float* __restrict__ x,
                                                       float* __restrict__ out,
                                                       int interleaved) {
    const int lane = threadIdx.x & 63;
    const int b = blockIdx.x * (blockDim.x >> 6) + (threadIdx.x >> 6);  // batch idx

    const float TANH_R = 0.46211715726f;   // tanh(0.5)
    const float alpha = 0.5f * x[b];
    const float c1 = alpha * (1.0f + TANH_R);   // alpha * e^r / cosh r

    // 63-step recurrence, fully unrolled (sqrt(n), rsqrt(n+1) fold to literals)
    float pm1 = 1.0f;           // psi_{n-1} -> starts as psi_0
    float p   = c1;             // psi_1 = c1 * psi_0
    float v = (lane == 0) ? 1.0f : 0.0f;
    if (lane == 1) v = p;
    #pragma unroll
    for (int n = 1; n < DIM - 1; ++n) {
        float pn = (c1 * p - TANH_R * sqrtf((float)n) * pm1) * rsqrtf((float)(n + 1));
        pm1 = p;
        p = pn;
        if (lane == n + 1) v = pn;
    }

    // normalize
    float n2 = v * v;
    #pragma unroll
    for (int off = 32; off; off >>= 1) n2 += __shfl_xor(n2, off, 64);
    v *= rsqrtf(n2);

    // column values for this lane's two columns (2c, 2c+1), c = lane&31
    const int cp = lane & 31;
    const int rs = lane >> 5;                   // row-select within a pair
    float pc0 = __shfl(v, 2 * cp, 64);
    float pc1 = __shfl(v, 2 * cp + 1, 64);

    if (interleaved) {
        // complex64: (re, im) pairs, im = 0. vf4 = 2 complex elements.
        vf4* o4 = (vf4*)out + (size_t)b * (DIM * DIM / 2);
        #pragma unroll
        for (int i = 0; i < DIM / 2; ++i) {
            int row = 2 * i + rs;
            float vr = __shfl(v, row, 64);
            vf4 val = {vr * pc0, 0.f, vr * pc1, 0.f};
            __builtin_nontemporal_store(val, &o4[row * (DIM / 2) + cp]);
        }
    } else {
        // real-only float buffer (imag of rho is exactly 0)
        vf2* o2 = (vf2*)out + (size_t)b * (DIM * DIM / 2);
        #pragma unroll
        for (int i = 0; i < DIM / 2; ++i) {
            int row = 2 * i + rs;
            float vr = __shfl(v, row, 64);
            vf2 val = {vr * pc0, vr * pc1};
            __builtin_nontemporal_store(val, &o2[row * (DIM / 2) + cp]);
        }
    }
}

extern "C" void kernel_launch(void* const* d_in, const int* in_sizes, int n_in,
                              void* d_out, int out_size, void* d_ws, size_t ws_size,
                              hipStream_t stream) {
    const float* x = (const float*)d_in[0];   // (4096,) float32
    float* out = (float*)d_out;

    const int N = BATCH * DIM * DIM;
    const int interleaved = (out_size >= 2 * N) ? 1 : 0;

    qencoder_kernel<<<BATCH / 4, 256, 0, stream>>>(x, out, interleaved);
}

// Round 6
// 77.669 us; speedup vs baseline: 1.7733x; 1.0066x over previous
//
#include <hip/hip_runtime.h>
#include <math.h>

#define DIM 64
#define BATCH 4096

// clang-native vector types (HIP's float4 is a class; the nontemporal builtin
// requires a true vector-of-scalars type)
typedef float vf4 __attribute__((ext_vector_type(4)));

// One wave per batch element. Closed-form amplitudes of psi = D(alpha) S(r) |0>:
//   psi_{n+1} = (alpha*(1+tanh r)*psi_n - tanh r*sqrt(n)*psi_{n-1}) / sqrt(n+1)
// (from (cosh r * a + sinh r * a^dag) psi = alpha e^r psi; psi_0 = 1, normalize after).
// All 64 lanes run the 63-step recurrence redundantly (wave-uniform VALU, no
// shuffles in the chain); lane n latches psi_n. Then butterfly-normalize and
// write rho[b][i][j] = psi_i psi_j (imag exactly 0 -> harness compares the
// real-element buffer; R1 fault proved out_size == B*DIM*DIM floats).
// Store path: 16 B/lane vf4 nontemporal stores, 1 KB fully-coalesced per
// instruction, 16 store insts/wave (4 rows per iteration).
__global__ __launch_bounds__(256) void qencoder_kernel(const float* __restrict__ x,
                                                       float* __restrict__ out,
                                                       int interleaved) {
    const int lane = threadIdx.x & 63;
    const int b = blockIdx.x * (blockDim.x >> 6) + (threadIdx.x >> 6);  // batch idx

    const float TANH_R = 0.46211715726f;   // tanh(0.5)
    const float alpha = 0.5f * x[b];
    const float c1 = alpha * (1.0f + TANH_R);   // alpha * e^r / cosh r

    // 63-step recurrence, fully unrolled (sqrt(n), rsqrt(n+1) fold to literals)
    float pm1 = 1.0f;           // psi_{n-1} -> starts as psi_0
    float p   = c1;             // psi_1 = c1 * psi_0
    float v = (lane == 0) ? 1.0f : 0.0f;
    if (lane == 1) v = p;
    #pragma unroll
    for (int n = 1; n < DIM - 1; ++n) {
        float pn = (c1 * p - TANH_R * sqrtf((float)n) * pm1) * rsqrtf((float)(n + 1));
        pm1 = p;
        p = pn;
        if (lane == n + 1) v = pn;
    }

    // normalize
    float n2 = v * v;
    #pragma unroll
    for (int off = 32; off; off >>= 1) n2 += __shfl_xor(n2, off, 64);
    v *= rsqrtf(n2);

    if (interleaved) {
        // complex64: (re, im) pairs, im = 0. vf4 = 2 complex elements.
        // (defensive path — evidence says out is real-only)
        const int cp = lane & 31;
        const int rs = lane >> 5;
        float pc0 = __shfl(v, 2 * cp, 64);
        float pc1 = __shfl(v, 2 * cp + 1, 64);
        vf4* o4 = (vf4*)out + (size_t)b * (DIM * DIM / 2);
        #pragma unroll
        for (int i = 0; i < DIM / 2; ++i) {
            int row = 2 * i + rs;
            float vr = __shfl(v, row, 64);
            vf4 val = {vr * pc0, 0.f, vr * pc1, 0.f};
            __builtin_nontemporal_store(val, &o4[row * (DIM / 2) + cp]);
        }
    } else {
        // real-only float buffer: lane covers cols [4c,4c+4) of row 4i+rq
        const int c  = lane & 15;
        const int rq = lane >> 4;
        float pc0 = __shfl(v, 4 * c + 0, 64);
        float pc1 = __shfl(v, 4 * c + 1, 64);
        float pc2 = __shfl(v, 4 * c + 2, 64);
        float pc3 = __shfl(v, 4 * c + 3, 64);
        vf4* o4 = (vf4*)out + (size_t)b * (DIM * DIM / 4);
        #pragma unroll
        for (int i = 0; i < DIM / 4; ++i) {
            int row = 4 * i + rq;
            float vr = __shfl(v, row, 64);
            vf4 val = {vr * pc0, vr * pc1, vr * pc2, vr * pc3};
            __builtin_nontemporal_store(val, &o4[row * (DIM / 4) + c]);
        }
    }
}

extern "C" void kernel_launch(void* const* d_in, const int* in_sizes, int n_in,
                              void* d_out, int out_size, void* d_ws, size_t ws_size,
                              hipStream_t stream) {
    const float* x = (const float*)d_in[0];   // (4096,) float32
    float* out = (float*)d_out;

    const int N = BATCH * DIM * DIM;
    const int interleaved = (out_size >= 2 * N) ? 1 : 0;

    qencoder_kernel<<<BATCH / 4, 256, 0, stream>>>(x, out, interleaved);
}